// Round 1
// baseline (1524.876 us; speedup 1.0000x reference)
//
#include <hip/hip_runtime.h>
#include <hip/hip_bf16.h>
#include <math.h>

using bf16 = __hip_bfloat16;
typedef __attribute__((ext_vector_type(8))) short s16x8;
typedef __attribute__((ext_vector_type(4))) float f32x4;

#define NEG_INF_F (-1e30f)

// ---------- constants for this problem ----------
static constexpr int BATCH = 16;
static constexpr int LC = 2048;
static constexpr int LQ = 512;
static constexpr int DIM = 512;
static constexpr int FEAT = 2048;          // 4*DIM
static constexpr int MC = BATCH * LC;      // 32768
static constexpr int MQ = BATCH * LQ;      // 8192

__device__ __forceinline__ float bfs2f(short s) {
    union { float f; unsigned u; } x;
    x.u = ((unsigned)(unsigned short)s) << 16;
    return x.f;
}
__device__ __forceinline__ short f2bfs(float f) {
    bf16 h = __float2bfloat16(f);
    short s; __builtin_memcpy(&s, &h, 2);
    return s;
}

// ---------- fp32 -> bf16 convert ----------
__global__ __launch_bounds__(256) void cvt_f32_bf16(const float* __restrict__ in,
                                                    bf16* __restrict__ out, int n) {
    int i = (blockIdx.x * 256 + threadIdx.x) * 4;
    if (i + 3 < n) {
        float4 v = *(const float4*)(in + i);
        ushort4 o;
        o.x = (unsigned short)f2bfs(v.x);
        o.y = (unsigned short)f2bfs(v.y);
        o.z = (unsigned short)f2bfs(v.z);
        o.w = (unsigned short)f2bfs(v.w);
        *(ushort4*)(out + i) = o;
    } else {
        for (int k = i; k < n; k++) out[k] = __float2bfloat16(in[k]);
    }
}

// ---------- per-batch transpose: Q (B,LQ,DIM) f32 -> Qt (B,DIM,LQ) bf16 ----------
__global__ __launch_bounds__(256) void transpose_q(const float* __restrict__ Q,
                                                   bf16* __restrict__ Qt) {
    __shared__ float t[32][33];
    const int b = blockIdx.z;
    const int q0 = blockIdx.x * 32, d0 = blockIdx.y * 32;
    const int tx = threadIdx.x, ty = threadIdx.y; // 32 x 8
    const float* Qb = Q + (long)b * LQ * DIM;
    bf16* Qtb = Qt + (long)b * DIM * LQ;
#pragma unroll
    for (int i = 0; i < 32; i += 8)
        t[ty + i][tx] = Qb[(long)(q0 + ty + i) * DIM + d0 + tx];
    __syncthreads();
#pragma unroll
    for (int i = 0; i < 32; i += 8)
        Qtb[(long)(d0 + ty + i) * LQ + q0 + tx] = __float2bfloat16(t[tx][ty + i]);
}

// ---------- generic bf16 MFMA GEMM: Out[M,N] = A[M,K] @ B[N,K]^T, modal epilogue ----------
enum { MODE_PLAIN = 0, MODE_BIAS_LRELU = 1, MODE_TANH_F32 = 2, MODE_GATE_OUT = 3 };

template <int MODE>
__global__ __launch_bounds__(256)
void gemm_bt(const bf16* __restrict__ A, const bf16* __restrict__ B,
             void* __restrict__ Out,
             const float* __restrict__ bias,
             const float* __restrict__ fuse_f32,
             const bf16* __restrict__ catb,
             const int* __restrict__ cmask,
             int N, int K,
             long strideA, long strideB, long strideO) {
    constexpr int BM = 128, BN = 128, BK = 32;
    __shared__ __align__(16) bf16 As[BM * BK];
    __shared__ __align__(16) bf16 Bs[BN * BK];

    const int z = blockIdx.z;
    const bf16* Ab = A + (long)z * strideA;
    const bf16* Bb = B + (long)z * strideB;

    const int tid = threadIdx.x;
    const int wave = tid >> 6, lane = tid & 63;
    const int wm = (wave >> 1) * 64, wn = (wave & 1) * 64;
    const int lrow = lane & 15, lq = lane >> 4;

    const int bm0 = blockIdx.y * BM;
    const int bn0 = blockIdx.x * BN;

    // staging: each thread DMAs 16B; 256 thr * 16B = 4KB = 64 rows of 64B
    const int srow = tid >> 2;
    const int scol = (tid & 3) * 8;

    const bf16* ag = Ab + (long)(bm0 + srow) * K + scol;
    const bf16* bg = Bb + (long)(bn0 + srow) * K + scol;
    bf16* asl = &As[srow * BK + scol];   // byte offset = tid*16: contiguous in lane order
    bf16* bsl = &Bs[srow * BK + scol];
    const long skip64 = (long)64 * K;

    f32x4 acc[4][4];
#pragma unroll
    for (int i = 0; i < 4; i++)
#pragma unroll
        for (int j = 0; j < 4; j++) acc[i][j] = (f32x4){0.f, 0.f, 0.f, 0.f};

    for (int k0 = 0; k0 < K; k0 += BK) {
        __builtin_amdgcn_global_load_lds((const __attribute__((address_space(1))) void*)ag,
                                         (__attribute__((address_space(3))) void*)asl, 16, 0, 0);
        __builtin_amdgcn_global_load_lds((const __attribute__((address_space(1))) void*)(ag + skip64),
                                         (__attribute__((address_space(3))) void*)(asl + 64 * BK), 16, 0, 0);
        __builtin_amdgcn_global_load_lds((const __attribute__((address_space(1))) void*)bg,
                                         (__attribute__((address_space(3))) void*)bsl, 16, 0, 0);
        __builtin_amdgcn_global_load_lds((const __attribute__((address_space(1))) void*)(bg + skip64),
                                         (__attribute__((address_space(3))) void*)(bsl + 64 * BK), 16, 0, 0);
        ag += BK; bg += BK;
        __syncthreads();

        s16x8 af[4], bfv[4];
#pragma unroll
        for (int f = 0; f < 4; f++)
            af[f] = *(const s16x8*)&As[(wm + f * 16 + lrow) * BK + lq * 8];
#pragma unroll
        for (int f = 0; f < 4; f++)
            bfv[f] = *(const s16x8*)&Bs[(wn + f * 16 + lrow) * BK + lq * 8];

#pragma unroll
        for (int i = 0; i < 4; i++)
#pragma unroll
            for (int j = 0; j < 4; j++)
                acc[i][j] = __builtin_amdgcn_mfma_f32_16x16x32_bf16(af[i], bfv[j], acc[i][j], 0, 0, 0);
        __syncthreads();
    }

    // epilogue: C/D layout col=lane&15, row=(lane>>4)*4+reg  [m89/m91-verified]
#pragma unroll
    for (int i = 0; i < 4; i++) {
#pragma unroll
        for (int j = 0; j < 4; j++) {
            const int n = bn0 + wn + j * 16 + lrow;
            const float bn_bias = (MODE == MODE_PLAIN) ? 0.f : bias[n];
#pragma unroll
            for (int r = 0; r < 4; r++) {
                const int m = bm0 + wm + i * 16 + lq * 4 + r;
                const long off = (long)z * strideO + (long)m * N + n;
                float v = acc[i][j][r];
                if (MODE == MODE_PLAIN) {
                    ((bf16*)Out)[off] = __float2bfloat16(v);
                } else if (MODE == MODE_BIAS_LRELU) {
                    v += bn_bias;
                    v = v > 0.f ? v : 0.01f * v;
                    ((bf16*)Out)[off] = __float2bfloat16(v);
                } else if (MODE == MODE_TANH_F32) {
                    ((float*)Out)[off] = tanhf(v + bn_bias);
                } else { // MODE_GATE_OUT
                    const float g = 1.f / (1.f + __expf(-(v + bn_bias)));
                    const float f = fuse_f32[off];
                    const float c = __bfloat162float(catb[off]);
                    ((float*)Out)[off] = cmask[m] ? (g * f + (1.f - g) * c) : NEG_INF_F;
                }
            }
        }
    }
}

// ---------- masked row softmax over LQ=512, in place on bf16 S ----------
__global__ __launch_bounds__(256) void softmax_rows(bf16* __restrict__ S,
                                                    const int* __restrict__ Cmask,
                                                    const int* __restrict__ Qmask) {
    const int row = blockIdx.x;         // 0 .. B*LC-1
    const int b = row >> 11;            // LC = 2048
    const int tid = threadIdx.x;
    bf16* srow = S + (long)row * LQ;
    const int* qm = Qmask + b * LQ;
    __shared__ float red[8];

    if (Cmask[row] == 0) {
        // ref: all logits identical (-1e30) -> uniform softmax = 1/512 exactly
        const bf16 u = __float2bfloat16(1.0f / 512.0f);
        srow[tid] = u;
        srow[tid + 256] = u;
        return;
    }
    const int q0 = qm[tid], q1 = qm[tid + 256];
    float v0 = q0 ? __bfloat162float(srow[tid]) : -3e38f;
    float v1 = q1 ? __bfloat162float(srow[tid + 256]) : -3e38f;
    float mx = fmaxf(v0, v1);
#pragma unroll
    for (int o = 32; o > 0; o >>= 1) mx = fmaxf(mx, __shfl_down(mx, o, 64));
    const int wave = tid >> 6, lane = tid & 63;
    if (lane == 0) red[wave] = mx;
    __syncthreads();
    const float m4 = fmaxf(fmaxf(red[0], red[1]), fmaxf(red[2], red[3]));
    float e0 = q0 ? __expf(v0 - m4) : 0.f;
    float e1 = q1 ? __expf(v1 - m4) : 0.f;
    float s = e0 + e1;
#pragma unroll
    for (int o = 32; o > 0; o >>= 1) s += __shfl_down(s, o, 64);
    if (lane == 0) red[4 + wave] = s;
    __syncthreads();
    const float tot = red[4] + red[5] + red[6] + red[7];
    if (!(tot > 0.f)) { // degenerate: all Qmask zero -> ref gives uniform
        const bf16 u = __float2bfloat16(1.0f / 512.0f);
        srow[tid] = u;
        srow[tid + 256] = u;
        return;
    }
    const float inv = 1.0f / tot;
    srow[tid] = __float2bfloat16(e0 * inv);
    srow[tid + 256] = __float2bfloat16(e1 * inv);
}

// ---------- build cat = [C | attn | attn-C | attn*C] (bf16) ----------
__global__ __launch_bounds__(256) void build_cat(const bf16* __restrict__ Cb,
                                                 const bf16* __restrict__ attn,
                                                 bf16* __restrict__ cat) {
    const long t = (long)blockIdx.x * 256 + threadIdx.x;
    const int m = (int)(t >> 6);
    const int c = (int)(t & 63) << 3;
    const s16x8 cv = *(const s16x8*)((const short*)Cb + (long)m * DIM + c);
    const s16x8 av = *(const s16x8*)((const short*)attn + (long)m * DIM + c);
    s16x8 dv, pv;
#pragma unroll
    for (int i = 0; i < 8; i++) {
        const float cf = bfs2f(cv[i]);
        const float af = bfs2f(av[i]);
        dv[i] = f2bfs(af - cf);
        pv[i] = f2bfs(af * cf);
    }
    short* rowp = (short*)cat + (long)m * FEAT + c;
    *(s16x8*)(rowp) = cv;
    *(s16x8*)(rowp + 512) = av;
    *(s16x8*)(rowp + 1024) = dv;
    *(s16x8*)(rowp + 1536) = pv;
}

extern "C" void kernel_launch(void* const* d_in, const int* in_sizes, int n_in,
                              void* d_out, int out_size, void* d_ws, size_t ws_size,
                              hipStream_t stream) {
    (void)in_sizes; (void)n_in; (void)out_size; (void)ws_size;
    const float* C = (const float*)d_in[0];
    const float* Q = (const float*)d_in[1];
    const int* Cmask = (const int*)d_in[2];
    const int* Qmask = (const int*)d_in[3];
    const float* W1 = (const float*)d_in[4];
    const float* b1 = (const float*)d_in[5];
    const float* Wf = (const float*)d_in[6];
    const float* bfp = (const float*)d_in[7];
    const float* Wg = (const float*)d_in[8];
    const float* bgp = (const float*)d_in[9];
    float* out = (float*)d_out;

    // ---- workspace layout (bytes). Early temps overlap cat's 128MB footprint:
    // their last read (attn GEMM) precedes cat's first write (build_cat). ----
    char* ws = (char*)d_ws;
    bf16* catb = (bf16*)(ws + 0);                       // 134,217,728 B
    bf16* W1b  = (bf16*)(ws + 0);                       //     524,288
    bf16* Qb   = (bf16*)(ws + 524288);                  //   8,388,608
    bf16* Qt   = (bf16*)(ws + 8912896);                 //   8,388,608
    bf16* C_   = (bf16*)(ws + 17301504);                //  33,554,432
    bf16* Q_   = (bf16*)(ws + 50855936);                //   8,388,608
    bf16* S    = (bf16*)(ws + 59244544);                //  33,554,432 (ends 92,798,976 < 134,217,728)
    bf16* Cb   = (bf16*)(ws + 134217728);               //  33,554,432
    bf16* attn = (bf16*)(ws + 167772160);               //  33,554,432
    bf16* Wfb  = (bf16*)(ws + 201326592);               //   8,388,608
    bf16* Wgb  = (bf16*)(ws + 209715200);               //   8,388,608  (total ~218MB)

    // 1. dtype conversions
    cvt_f32_bf16<<<256, 256, 0, stream>>>(W1, W1b, DIM * DIM);
    cvt_f32_bf16<<<4096, 256, 0, stream>>>(Wf, Wfb, FEAT * FEAT);
    cvt_f32_bf16<<<4096, 256, 0, stream>>>(Wg, Wgb, FEAT * FEAT);
    cvt_f32_bf16<<<16384, 256, 0, stream>>>(C, Cb, MC * DIM);
    cvt_f32_bf16<<<4096, 256, 0, stream>>>(Q, Qb, MQ * DIM);
    transpose_q<<<dim3(16, 16, 16), dim3(32, 8), 0, stream>>>(Q, Qt);

    // 2. C_ = lrelu(C @ W1^T + b1), Q_ = lrelu(Q @ W1^T + b1)  (bf16 out)
    gemm_bt<MODE_BIAS_LRELU><<<dim3(4, 256, 1), 256, 0, stream>>>(
        Cb, W1b, C_, b1, nullptr, nullptr, nullptr, DIM, DIM, 0, 0, 0);
    gemm_bt<MODE_BIAS_LRELU><<<dim3(4, 64, 1), 256, 0, stream>>>(
        Qb, W1b, Q_, b1, nullptr, nullptr, nullptr, DIM, DIM, 0, 0, 0);

    // 3. S[b] = C_[b] @ Q_[b]^T  (batched, bf16 logits)
    gemm_bt<MODE_PLAIN><<<dim3(4, 16, 16), 256, 0, stream>>>(
        C_, Q_, S, nullptr, nullptr, nullptr, nullptr, LQ, DIM,
        (long)LC * DIM, (long)LQ * DIM, (long)LC * LQ);

    // 4. masked softmax over q (in place)
    softmax_rows<<<MC, 256, 0, stream>>>(S, Cmask, Qmask);

    // 5. attn[b] = S[b] @ Q[b]   (B-operand = Qt, batched)
    gemm_bt<MODE_PLAIN><<<dim3(4, 16, 16), 256, 0, stream>>>(
        S, Qt, attn, nullptr, nullptr, nullptr, nullptr, DIM, LQ,
        (long)LC * LQ, (long)DIM * LQ, (long)LC * DIM);

    // 6. cat = [C | attn | attn-C | attn*C]
    build_cat<<<8192, 256, 0, stream>>>(Cb, attn, catb);

    // 7. fuse = tanh(cat @ Wf^T + bf)  -> fp32 into d_out (scratch reuse)
    gemm_bt<MODE_TANH_F32><<<dim3(16, 256, 1), 256, 0, stream>>>(
        catb, Wfb, out, bfp, nullptr, nullptr, nullptr, FEAT, FEAT, 0, 0, 0);

    // 8. gate GEMM + final combine + Cmask -> d_out fp32
    gemm_bt<MODE_GATE_OUT><<<dim3(16, 256, 1), 256, 0, stream>>>(
        catb, Wgb, out, bgp, (const float*)out, catb, Cmask, FEAT, FEAT, 0, 0, 0);
}

// Round 2
// 1179.298 us; speedup vs baseline: 1.2930x; 1.2930x over previous
//
#include <hip/hip_runtime.h>
#include <hip/hip_bf16.h>
#include <math.h>

using bf16 = __hip_bfloat16;
typedef __attribute__((ext_vector_type(8))) short s16x8;
typedef __attribute__((ext_vector_type(4))) float f32x4;

#define NEG_INF_F (-1e30f)

// ---------- constants for this problem ----------
static constexpr int BATCH = 16;
static constexpr int LC = 2048;
static constexpr int LQ = 512;
static constexpr int DIM = 512;
static constexpr int FEAT = 2048;          // 4*DIM
static constexpr int MC = BATCH * LC;      // 32768
static constexpr int MQ = BATCH * LQ;      // 8192

__device__ __forceinline__ float bfs2f(short s) {
    union { float f; unsigned u; } x;
    x.u = ((unsigned)(unsigned short)s) << 16;
    return x.f;
}
__device__ __forceinline__ short f2bfs(float f) {
    bf16 h = __float2bfloat16(f);
    short s; __builtin_memcpy(&s, &h, 2);
    return s;
}

#define GLL(gp, lp) __builtin_amdgcn_global_load_lds( \
    (const __attribute__((address_space(1))) void*)(gp), \
    (__attribute__((address_space(3))) void*)(lp), 16, 0, 0)

// ---------- fp32 -> bf16 convert ----------
__global__ __launch_bounds__(256) void cvt_f32_bf16(const float* __restrict__ in,
                                                    bf16* __restrict__ out, int n) {
    int i = (blockIdx.x * 256 + threadIdx.x) * 4;
    if (i + 3 < n) {
        float4 v = *(const float4*)(in + i);
        ushort4 o;
        o.x = (unsigned short)f2bfs(v.x);
        o.y = (unsigned short)f2bfs(v.y);
        o.z = (unsigned short)f2bfs(v.z);
        o.w = (unsigned short)f2bfs(v.w);
        *(ushort4*)(out + i) = o;
    } else {
        for (int k = i; k < n; k++) out[k] = __float2bfloat16(in[k]);
    }
}

// ---------- per-batch transpose: Q (B,LQ,DIM) f32 -> Qt (B,DIM,LQ) bf16 ----------
__global__ __launch_bounds__(256) void transpose_q(const float* __restrict__ Q,
                                                   bf16* __restrict__ Qt) {
    __shared__ float t[32][33];
    const int b = blockIdx.z;
    const int q0 = blockIdx.x * 32, d0 = blockIdx.y * 32;
    const int tx = threadIdx.x, ty = threadIdx.y; // 32 x 8
    const float* Qb = Q + (long)b * LQ * DIM;
    bf16* Qtb = Qt + (long)b * DIM * LQ;
#pragma unroll
    for (int i = 0; i < 32; i += 8)
        t[ty + i][tx] = Qb[(long)(q0 + ty + i) * DIM + d0 + tx];
    __syncthreads();
#pragma unroll
    for (int i = 0; i < 32; i += 8)
        Qtb[(long)(d0 + ty + i) * LQ + q0 + tx] = __float2bfloat16(t[tx][ty + i]);
}

// ---------- generic bf16 MFMA GEMM: Out[M,N] = A[M,K] @ B[N,K]^T ----------
enum { MODE_PLAIN = 0, MODE_BIAS_LRELU = 1 };

template <int MODE>
__global__ __launch_bounds__(256)
void gemm_bt(const bf16* __restrict__ A, const bf16* __restrict__ B,
             void* __restrict__ Out,
             const float* __restrict__ bias,
             int N, int K,
             long strideA, long strideB, long strideO) {
    constexpr int BM = 128, BN = 128, BK = 32;
    __shared__ __align__(16) bf16 As[BM * BK];
    __shared__ __align__(16) bf16 Bs[BN * BK];

    const int z = blockIdx.z;
    const bf16* Ab = A + (long)z * strideA;
    const bf16* Bb = B + (long)z * strideB;

    const int tid = threadIdx.x;
    const int wave = tid >> 6, lane = tid & 63;
    const int wm = (wave >> 1) * 64, wn = (wave & 1) * 64;
    const int lrow = lane & 15, lq = lane >> 4;

    const int bm0 = blockIdx.y * BM;
    const int bn0 = blockIdx.x * BN;

    const int srow = tid >> 2;
    const int scol = (tid & 3) * 8;

    const bf16* ag = Ab + (long)(bm0 + srow) * K + scol;
    const bf16* bg = Bb + (long)(bn0 + srow) * K + scol;
    bf16* asl = &As[srow * BK + scol];   // byte offset = tid*16: contiguous in lane order
    bf16* bsl = &Bs[srow * BK + scol];
    const long skip64 = (long)64 * K;

    f32x4 acc[4][4];
#pragma unroll
    for (int i = 0; i < 4; i++)
#pragma unroll
        for (int j = 0; j < 4; j++) acc[i][j] = (f32x4){0.f, 0.f, 0.f, 0.f};

    for (int k0 = 0; k0 < K; k0 += BK) {
        GLL(ag, asl);
        GLL(ag + skip64, asl + 64 * BK);
        GLL(bg, bsl);
        GLL(bg + skip64, bsl + 64 * BK);
        ag += BK; bg += BK;
        __syncthreads();

        s16x8 af[4], bfv[4];
#pragma unroll
        for (int f = 0; f < 4; f++)
            af[f] = *(const s16x8*)&As[(wm + f * 16 + lrow) * BK + lq * 8];
#pragma unroll
        for (int f = 0; f < 4; f++)
            bfv[f] = *(const s16x8*)&Bs[(wn + f * 16 + lrow) * BK + lq * 8];

#pragma unroll
        for (int i = 0; i < 4; i++)
#pragma unroll
            for (int j = 0; j < 4; j++)
                acc[i][j] = __builtin_amdgcn_mfma_f32_16x16x32_bf16(af[i], bfv[j], acc[i][j], 0, 0, 0);
        __syncthreads();
    }

    // epilogue: C/D layout col=lane&15, row=(lane>>4)*4+reg  [m89/m91-verified]
#pragma unroll
    for (int i = 0; i < 4; i++) {
#pragma unroll
        for (int j = 0; j < 4; j++) {
            const int n = bn0 + wn + j * 16 + lrow;
            const float bn_bias = (MODE == MODE_PLAIN) ? 0.f : bias[n];
#pragma unroll
            for (int r = 0; r < 4; r++) {
                const int m = bm0 + wm + i * 16 + lq * 4 + r;
                const long off = (long)z * strideO + (long)m * N + n;
                float v = acc[i][j][r];
                if (MODE == MODE_PLAIN) {
                    ((bf16*)Out)[off] = __float2bfloat16(v);
                } else { // MODE_BIAS_LRELU
                    v += bn_bias;
                    v = v > 0.f ? v : 0.01f * v;
                    ((bf16*)Out)[off] = __float2bfloat16(v);
                }
            }
        }
    }
}

// ---------- fused dual GEMM: fuse = tanh(cat@Wf^T+bf), gate = sigm(cat@Wg^T+bg),
//            out = Cmask ? gate*fuse + (1-gate)*cat : -1e30  (fp32) ----------
__global__ __launch_bounds__(256, 2)
void gemm_dual(const bf16* __restrict__ A, const bf16* __restrict__ Bf_,
               const bf16* __restrict__ Bg_, float* __restrict__ Out,
               const float* __restrict__ biasf, const float* __restrict__ biasg,
               const bf16* __restrict__ catb, const int* __restrict__ cmask) {
    constexpr int BM = 128, BN = 128, BK = 32;
    constexpr int N = FEAT, K = FEAT;
    __shared__ __align__(16) bf16 As[BM * BK];
    __shared__ __align__(16) bf16 Bfs[BN * BK];
    __shared__ __align__(16) bf16 Bgs[BN * BK];

    const int tid = threadIdx.x;
    const int wave = tid >> 6, lane = tid & 63;
    const int wm = (wave >> 1) * 64, wn = (wave & 1) * 64;
    const int lrow = lane & 15, lq = lane >> 4;

    const int bm0 = blockIdx.y * BM;
    const int bn0 = blockIdx.x * BN;

    const int srow = tid >> 2;
    const int scol = (tid & 3) * 8;

    const bf16* ag  = A   + (long)(bm0 + srow) * K + scol;
    const bf16* bfg = Bf_ + (long)(bn0 + srow) * K + scol;
    const bf16* bgg = Bg_ + (long)(bn0 + srow) * K + scol;
    bf16* asl = &As[srow * BK + scol];
    bf16* bfl = &Bfs[srow * BK + scol];
    bf16* bgl = &Bgs[srow * BK + scol];
    const long skip64 = (long)64 * K;

    f32x4 accf[4][4], accg[4][4];
#pragma unroll
    for (int i = 0; i < 4; i++)
#pragma unroll
        for (int j = 0; j < 4; j++) {
            accf[i][j] = (f32x4){0.f, 0.f, 0.f, 0.f};
            accg[i][j] = (f32x4){0.f, 0.f, 0.f, 0.f};
        }

    for (int k0 = 0; k0 < K; k0 += BK) {
        GLL(ag, asl);
        GLL(ag + skip64, asl + 64 * BK);
        GLL(bfg, bfl);
        GLL(bfg + skip64, bfl + 64 * BK);
        GLL(bgg, bgl);
        GLL(bgg + skip64, bgl + 64 * BK);
        ag += BK; bfg += BK; bgg += BK;
        __syncthreads();

        s16x8 af[4];
#pragma unroll
        for (int f = 0; f < 4; f++)
            af[f] = *(const s16x8*)&As[(wm + f * 16 + lrow) * BK + lq * 8];

#pragma unroll
        for (int j = 0; j < 4; j++) {
            const s16x8 bff = *(const s16x8*)&Bfs[(wn + j * 16 + lrow) * BK + lq * 8];
            const s16x8 bgf = *(const s16x8*)&Bgs[(wn + j * 16 + lrow) * BK + lq * 8];
#pragma unroll
            for (int i = 0; i < 4; i++)
                accf[i][j] = __builtin_amdgcn_mfma_f32_16x16x32_bf16(af[i], bff, accf[i][j], 0, 0, 0);
#pragma unroll
            for (int i = 0; i < 4; i++)
                accg[i][j] = __builtin_amdgcn_mfma_f32_16x16x32_bf16(af[i], bgf, accg[i][j], 0, 0, 0);
        }
        __syncthreads();
    }

    // epilogue: both activations + gate blend + Cmask, single pass
#pragma unroll
    for (int j = 0; j < 4; j++) {
        const int n = bn0 + wn + j * 16 + lrow;
        const float bfb = biasf[n];
        const float bgb = biasg[n];
#pragma unroll
        for (int i = 0; i < 4; i++) {
#pragma unroll
            for (int r = 0; r < 4; r++) {
                const int m = bm0 + wm + i * 16 + lq * 4 + r;
                const long off = (long)m * N + n;
                const float vf = accf[i][j][r] + bfb;
                const float vg = accg[i][j][r] + bgb;
                // stable tanh: sign(x) * (1 - 2/(e^{2|x|}+1)); e=inf -> 1
                const float e = __expf(2.0f * fabsf(vf));
                const float th = copysignf(1.0f - 2.0f / (e + 1.0f), vf);
                const float g = 1.0f / (1.0f + __expf(-vg));
                const float c = __bfloat162float(catb[off]);
                Out[off] = cmask[m] ? (g * th + (1.0f - g) * c) : NEG_INF_F;
            }
        }
    }
}

// ---------- masked row softmax over LQ=512, in place on bf16 S ----------
__global__ __launch_bounds__(256) void softmax_rows(bf16* __restrict__ S,
                                                    const int* __restrict__ Cmask,
                                                    const int* __restrict__ Qmask) {
    const int row = blockIdx.x;         // 0 .. B*LC-1
    const int b = row >> 11;            // LC = 2048
    const int tid = threadIdx.x;
    bf16* srow = S + (long)row * LQ;
    const int* qm = Qmask + b * LQ;
    __shared__ float red[8];

    if (Cmask[row] == 0) {
        // ref: all logits identical (-1e30) -> uniform softmax = 1/512 exactly
        const bf16 u = __float2bfloat16(1.0f / 512.0f);
        srow[tid] = u;
        srow[tid + 256] = u;
        return;
    }
    const int q0 = qm[tid], q1 = qm[tid + 256];
    float v0 = q0 ? __bfloat162float(srow[tid]) : -3e38f;
    float v1 = q1 ? __bfloat162float(srow[tid + 256]) : -3e38f;
    float mx = fmaxf(v0, v1);
#pragma unroll
    for (int o = 32; o > 0; o >>= 1) mx = fmaxf(mx, __shfl_down(mx, o, 64));
    const int wave = tid >> 6, lane = tid & 63;
    if (lane == 0) red[wave] = mx;
    __syncthreads();
    const float m4 = fmaxf(fmaxf(red[0], red[1]), fmaxf(red[2], red[3]));
    float e0 = q0 ? __expf(v0 - m4) : 0.f;
    float e1 = q1 ? __expf(v1 - m4) : 0.f;
    float s = e0 + e1;
#pragma unroll
    for (int o = 32; o > 0; o >>= 1) s += __shfl_down(s, o, 64);
    if (lane == 0) red[4 + wave] = s;
    __syncthreads();
    const float tot = red[4] + red[5] + red[6] + red[7];
    if (!(tot > 0.f)) { // degenerate: all Qmask zero -> ref gives uniform
        const bf16 u = __float2bfloat16(1.0f / 512.0f);
        srow[tid] = u;
        srow[tid + 256] = u;
        return;
    }
    const float inv = 1.0f / tot;
    srow[tid] = __float2bfloat16(e0 * inv);
    srow[tid + 256] = __float2bfloat16(e1 * inv);
}

// ---------- build cat = [C | attn | attn-C | attn*C] (bf16) ----------
__global__ __launch_bounds__(256) void build_cat(const bf16* __restrict__ Cb,
                                                 const bf16* __restrict__ attn,
                                                 bf16* __restrict__ cat) {
    const long t = (long)blockIdx.x * 256 + threadIdx.x;
    const int m = (int)(t >> 6);
    const int c = (int)(t & 63) << 3;
    const s16x8 cv = *(const s16x8*)((const short*)Cb + (long)m * DIM + c);
    const s16x8 av = *(const s16x8*)((const short*)attn + (long)m * DIM + c);
    s16x8 dv, pv;
#pragma unroll
    for (int i = 0; i < 8; i++) {
        const float cf = bfs2f(cv[i]);
        const float af = bfs2f(av[i]);
        dv[i] = f2bfs(af - cf);
        pv[i] = f2bfs(af * cf);
    }
    short* rowp = (short*)cat + (long)m * FEAT + c;
    *(s16x8*)(rowp) = cv;
    *(s16x8*)(rowp + 512) = av;
    *(s16x8*)(rowp + 1024) = dv;
    *(s16x8*)(rowp + 1536) = pv;
}

extern "C" void kernel_launch(void* const* d_in, const int* in_sizes, int n_in,
                              void* d_out, int out_size, void* d_ws, size_t ws_size,
                              hipStream_t stream) {
    (void)in_sizes; (void)n_in; (void)out_size; (void)ws_size;
    const float* C = (const float*)d_in[0];
    const float* Q = (const float*)d_in[1];
    const int* Cmask = (const int*)d_in[2];
    const int* Qmask = (const int*)d_in[3];
    const float* W1 = (const float*)d_in[4];
    const float* b1 = (const float*)d_in[5];
    const float* Wf = (const float*)d_in[6];
    const float* bfp = (const float*)d_in[7];
    const float* Wg = (const float*)d_in[8];
    const float* bgp = (const float*)d_in[9];
    float* out = (float*)d_out;

    // ---- workspace layout (bytes). Early temps overlap cat's 128MB footprint:
    // their last read (attn GEMM) precedes cat's first write (build_cat). ----
    char* ws = (char*)d_ws;
    bf16* catb = (bf16*)(ws + 0);                       // 134,217,728 B
    bf16* W1b  = (bf16*)(ws + 0);                       //     524,288
    bf16* Qb   = (bf16*)(ws + 524288);                  //   8,388,608
    bf16* Qt   = (bf16*)(ws + 8912896);                 //   8,388,608
    bf16* C_   = (bf16*)(ws + 17301504);                //  33,554,432
    bf16* Q_   = (bf16*)(ws + 50855936);                //   8,388,608
    bf16* S    = (bf16*)(ws + 59244544);                //  33,554,432 (ends 92,798,976 < 134,217,728)
    bf16* Cb   = (bf16*)(ws + 134217728);               //  33,554,432
    bf16* attn = (bf16*)(ws + 167772160);               //  33,554,432
    bf16* Wfb  = (bf16*)(ws + 201326592);               //   8,388,608
    bf16* Wgb  = (bf16*)(ws + 209715200);               //   8,388,608  (total ~218MB)

    // 1. dtype conversions
    cvt_f32_bf16<<<256, 256, 0, stream>>>(W1, W1b, DIM * DIM);
    cvt_f32_bf16<<<4096, 256, 0, stream>>>(Wf, Wfb, FEAT * FEAT);
    cvt_f32_bf16<<<4096, 256, 0, stream>>>(Wg, Wgb, FEAT * FEAT);
    cvt_f32_bf16<<<16384, 256, 0, stream>>>(C, Cb, MC * DIM);
    cvt_f32_bf16<<<4096, 256, 0, stream>>>(Q, Qb, MQ * DIM);
    transpose_q<<<dim3(16, 16, 16), dim3(32, 8), 0, stream>>>(Q, Qt);

    // 2. C_ = lrelu(C @ W1^T + b1), Q_ = lrelu(Q @ W1^T + b1)  (bf16 out)
    gemm_bt<MODE_BIAS_LRELU><<<dim3(4, 256, 1), 256, 0, stream>>>(
        Cb, W1b, C_, b1, DIM, DIM, 0, 0, 0);
    gemm_bt<MODE_BIAS_LRELU><<<dim3(4, 64, 1), 256, 0, stream>>>(
        Qb, W1b, Q_, b1, DIM, DIM, 0, 0, 0);

    // 3. S[b] = C_[b] @ Q_[b]^T  (batched, bf16 logits)
    gemm_bt<MODE_PLAIN><<<dim3(4, 16, 16), 256, 0, stream>>>(
        C_, Q_, S, nullptr, LQ, DIM,
        (long)LC * DIM, (long)LQ * DIM, (long)LC * LQ);

    // 4. masked softmax over q (in place)
    softmax_rows<<<MC, 256, 0, stream>>>(S, Cmask, Qmask);

    // 5. attn[b] = S[b] @ Q[b]   (B-operand = Qt, batched)
    gemm_bt<MODE_PLAIN><<<dim3(4, 16, 16), 256, 0, stream>>>(
        S, Qt, attn, nullptr, DIM, LQ,
        (long)LC * LQ, (long)DIM * LQ, (long)LC * DIM);

    // 6. cat = [C | attn | attn-C | attn*C]
    build_cat<<<8192, 256, 0, stream>>>(Cb, attn, catb);

    // 7+8 fused: out = Cmask ? sigm(cat@Wg^T+bg)*tanh(cat@Wf^T+bf)
    //                          + (1-sigm)*cat : -1e30   (fp32)
    gemm_dual<<<dim3(16, 256, 1), 256, 0, stream>>>(
        catb, Wfb, Wgb, out, bfp, bgp, catb, Cmask);
}

// Round 3
// 898.216 us; speedup vs baseline: 1.6977x; 1.3129x over previous
//
#include <hip/hip_runtime.h>
#include <hip/hip_bf16.h>
#include <math.h>

using bf16 = __hip_bfloat16;
typedef __attribute__((ext_vector_type(8))) short s16x8;
typedef __attribute__((ext_vector_type(4))) float f32x4;
typedef __attribute__((ext_vector_type(8))) int i32x8;
typedef __attribute__((ext_vector_type(4))) int i32x4;

#define NEG_INF_F (-1e30f)

// ---------- constants for this problem ----------
static constexpr int BATCH = 16;
static constexpr int LC = 2048;
static constexpr int LQ = 512;
static constexpr int DIM = 512;
static constexpr int FEAT = 2048;          // 4*DIM
static constexpr int MC = BATCH * LC;      // 32768
static constexpr int MQ = BATCH * LQ;      // 8192

__device__ __forceinline__ float bfs2f(short s) {
    union { float f; unsigned u; } x;
    x.u = ((unsigned)(unsigned short)s) << 16;
    return x.f;
}
__device__ __forceinline__ short f2bfs(float f) {
    bf16 h = __float2bfloat16(f);
    short s; __builtin_memcpy(&s, &h, 2);
    return s;
}
// OCP e4m3 byte -> float (decoder, epilogue only)
__device__ __forceinline__ float fp8_to_f(unsigned b) {
    const unsigned s = b >> 7, e = (b >> 3) & 15, m = b & 7;
    const int ee = e ? (int)e : 1;
    const int mm = e ? (int)(8 + m) : (int)m;
    union { unsigned u; float f; } sc; sc.u = (unsigned)(ee + 117) << 23; // 2^(ee-10)
    const float v = (float)mm * sc.f;
    return s ? -v : v;
}
// pack 8 floats -> 8 fp8 e4m3 bytes (saturating RNE via HW cvt)
__device__ __forceinline__ uint2 pk8fp8(float a0, float a1, float a2, float a3,
                                        float a4, float a5, float a6, float a7) {
    uint2 r;
    int w0 = __builtin_amdgcn_cvt_pk_fp8_f32(a0, a1, 0, false);
    w0 = __builtin_amdgcn_cvt_pk_fp8_f32(a2, a3, w0, true);
    int w1 = __builtin_amdgcn_cvt_pk_fp8_f32(a4, a5, 0, false);
    w1 = __builtin_amdgcn_cvt_pk_fp8_f32(a6, a7, w1, true);
    r.x = (unsigned)w0; r.y = (unsigned)w1;
    return r;
}

#define GLL(gp, lp) __builtin_amdgcn_global_load_lds( \
    (const __attribute__((address_space(1))) void*)(gp), \
    (__attribute__((address_space(3))) void*)(lp), 16, 0, 0)

// ---------- fp32 -> bf16 convert ----------
__global__ __launch_bounds__(256) void cvt_f32_bf16(const float* __restrict__ in,
                                                    bf16* __restrict__ out, int n) {
    int i = (blockIdx.x * 256 + threadIdx.x) * 4;
    if (i + 3 < n) {
        float4 v = *(const float4*)(in + i);
        ushort4 o;
        o.x = (unsigned short)f2bfs(v.x);
        o.y = (unsigned short)f2bfs(v.y);
        o.z = (unsigned short)f2bfs(v.z);
        o.w = (unsigned short)f2bfs(v.w);
        *(ushort4*)(out + i) = o;
    } else {
        for (int k = i; k < n; k++) out[k] = __float2bfloat16(in[k]);
    }
}

// ---------- fp32 -> fp8 e4m3 with x32 pre-scale (weights; MX scale 2^-5 compensates) ----------
__global__ __launch_bounds__(256) void cvt_f32_fp8_w(const float* __restrict__ in,
                                                     unsigned char* __restrict__ out, int n) {
    int i = (blockIdx.x * 256 + threadIdx.x) * 4;
    if (i >= n) return;
    float4 v = *(const float4*)(in + i);
    int w0 = __builtin_amdgcn_cvt_pk_fp8_f32(v.x * 32.f, v.y * 32.f, 0, false);
    w0 = __builtin_amdgcn_cvt_pk_fp8_f32(v.z * 32.f, v.w * 32.f, w0, true);
    *(int*)(out + i) = w0;
}

// ---------- per-batch transpose: Q (B,LQ,DIM) f32 -> Qt (B,DIM,LQ) bf16 ----------
__global__ __launch_bounds__(256) void transpose_q(const float* __restrict__ Q,
                                                   bf16* __restrict__ Qt) {
    __shared__ float t[32][33];
    const int b = blockIdx.z;
    const int q0 = blockIdx.x * 32, d0 = blockIdx.y * 32;
    const int tx = threadIdx.x, ty = threadIdx.y; // 32 x 8
    const float* Qb = Q + (long)b * LQ * DIM;
    bf16* Qtb = Qt + (long)b * DIM * LQ;
#pragma unroll
    for (int i = 0; i < 32; i += 8)
        t[ty + i][tx] = Qb[(long)(q0 + ty + i) * DIM + d0 + tx];
    __syncthreads();
#pragma unroll
    for (int i = 0; i < 32; i += 8)
        Qtb[(long)(d0 + ty + i) * LQ + q0 + tx] = __float2bfloat16(t[tx][ty + i]);
}

// ---------- generic bf16 MFMA GEMM: Out[M,N] = A[M,K] @ B[N,K]^T ----------
enum { MODE_PLAIN = 0, MODE_BIAS_LRELU = 1 };

template <int MODE>
__global__ __launch_bounds__(256)
void gemm_bt(const bf16* __restrict__ A, const bf16* __restrict__ B,
             void* __restrict__ Out,
             const float* __restrict__ bias,
             int N, int K,
             long strideA, long strideB, long strideO) {
    constexpr int BM = 128, BN = 128, BK = 32;
    __shared__ __align__(16) bf16 As[BM * BK];
    __shared__ __align__(16) bf16 Bs[BN * BK];

    const int z = blockIdx.z;
    const bf16* Ab = A + (long)z * strideA;
    const bf16* Bb = B + (long)z * strideB;

    const int tid = threadIdx.x;
    const int wave = tid >> 6, lane = tid & 63;
    const int wm = (wave >> 1) * 64, wn = (wave & 1) * 64;
    const int lrow = lane & 15, lq = lane >> 4;

    const int bm0 = blockIdx.y * BM;
    const int bn0 = blockIdx.x * BN;

    const int srow = tid >> 2;
    const int scol = (tid & 3) * 8;

    const bf16* ag = Ab + (long)(bm0 + srow) * K + scol;
    const bf16* bg = Bb + (long)(bn0 + srow) * K + scol;
    bf16* asl = &As[srow * BK + scol];   // byte offset = tid*16: contiguous in lane order
    bf16* bsl = &Bs[srow * BK + scol];
    const long skip64 = (long)64 * K;

    f32x4 acc[4][4];
#pragma unroll
    for (int i = 0; i < 4; i++)
#pragma unroll
        for (int j = 0; j < 4; j++) acc[i][j] = (f32x4){0.f, 0.f, 0.f, 0.f};

    for (int k0 = 0; k0 < K; k0 += BK) {
        GLL(ag, asl);
        GLL(ag + skip64, asl + 64 * BK);
        GLL(bg, bsl);
        GLL(bg + skip64, bsl + 64 * BK);
        ag += BK; bg += BK;
        __syncthreads();

        s16x8 af[4], bfv[4];
#pragma unroll
        for (int f = 0; f < 4; f++)
            af[f] = *(const s16x8*)&As[(wm + f * 16 + lrow) * BK + lq * 8];
#pragma unroll
        for (int f = 0; f < 4; f++)
            bfv[f] = *(const s16x8*)&Bs[(wn + f * 16 + lrow) * BK + lq * 8];

#pragma unroll
        for (int i = 0; i < 4; i++)
#pragma unroll
            for (int j = 0; j < 4; j++)
                acc[i][j] = __builtin_amdgcn_mfma_f32_16x16x32_bf16(af[i], bfv[j], acc[i][j], 0, 0, 0);
        __syncthreads();
    }

    // epilogue: C/D layout col=lane&15, row=(lane>>4)*4+reg  [m89/m91-verified]
#pragma unroll
    for (int i = 0; i < 4; i++) {
#pragma unroll
        for (int j = 0; j < 4; j++) {
            const int n = bn0 + wn + j * 16 + lrow;
            const float bn_bias = (MODE == MODE_PLAIN) ? 0.f : bias[n];
#pragma unroll
            for (int r = 0; r < 4; r++) {
                const int m = bm0 + wm + i * 16 + lq * 4 + r;
                const long off = (long)z * strideO + (long)m * N + n;
                float v = acc[i][j][r];
                if (MODE == MODE_PLAIN) {
                    ((bf16*)Out)[off] = __float2bfloat16(v);
                } else { // MODE_BIAS_LRELU
                    v += bn_bias;
                    v = v > 0.f ? v : 0.01f * v;
                    ((bf16*)Out)[off] = __float2bfloat16(v);
                }
            }
        }
    }
}

// ---------- fused dual GEMM, MX-fp8 K=128: fuse = tanh(cat@Wf^T+bf),
//            gate = sigm(cat@Wg^T+bg), out = Cmask ? g*fuse+(1-g)*cat : -1e30 ----------
// A = cat fp8 (scale 2^0, byte 127); B = weights pre-scaled x32 fp8 (MX scale 2^-5, byte 122).
// LDS tiles 128 rows x 128 B, 16B chunks XOR-swizzled: chunk c of row m at pos c^(m&7)
// (keeps global_load_lds lane-contiguous AND makes fragment ds_reads 2-way-only = free).
__global__ __launch_bounds__(256, 2)
void gemm_dual_fp8(const unsigned char* __restrict__ A8,
                   const unsigned char* __restrict__ Bf8,
                   const unsigned char* __restrict__ Bg8,
                   float* __restrict__ Out,
                   const float* __restrict__ biasf, const float* __restrict__ biasg,
                   const unsigned char* __restrict__ cat8,
                   const int* __restrict__ cmask) {
    constexpr int BM = 128, BN = 128;
    constexpr int N = FEAT, K = FEAT;   // K in bytes per row (fp8)
    __shared__ __align__(16) char As[BM * 128];
    __shared__ __align__(16) char Bfs[BN * 128];
    __shared__ __align__(16) char Bgs[BN * 128];

    const int tid = threadIdx.x;
    const int wave = tid >> 6, lane = tid & 63;
    const int wm = (wave >> 1) * 64, wn = (wave & 1) * 64;
    const int lrow = lane & 15, lq = lane >> 4;

    const int bm0 = blockIdx.y * BM;
    const int bn0 = blockIdx.x * BN;

    // ---- staging: thread t writes LDS chunk q=t+256r at byte q*16; that chunk
    // holds global row (r0+32r), k-bytes (p ^ (r0&7))*16 .. +16 ----
    const int p = tid & 7, r0 = tid >> 3;
    const int xo = (p ^ (r0 & 7)) * 16;
    const unsigned char* agp = A8 + (long)(bm0 + r0) * K + xo;
    const unsigned char* bfgp = Bf8 + (long)(bn0 + r0) * K + xo;
    const unsigned char* bggp = Bg8 + (long)(bn0 + r0) * K + xo;
    char* asl = As + tid * 16;
    char* bfl = Bfs + tid * 16;
    char* bgl = Bgs + tid * 16;
    const long rowskip = (long)32 * K;

    // ---- fragment ds_read offsets (loop-invariant): frag (row, kq=lq) halves h=0,1
    // stored at row*128 + ((lq*2+h)^(row&7))*16 ----
    int offA0[4], offA1[4], offB0[4], offB1[4];
#pragma unroll
    for (int f = 0; f < 4; f++) {
        const int ra = wm + f * 16 + lrow;
        offA0[f] = ra * 128 + (((lq * 2 + 0) ^ (ra & 7)) * 16);
        offA1[f] = ra * 128 + (((lq * 2 + 1) ^ (ra & 7)) * 16);
        const int rb = wn + f * 16 + lrow;
        offB0[f] = rb * 128 + (((lq * 2 + 0) ^ (rb & 7)) * 16);
        offB1[f] = rb * 128 + (((lq * 2 + 1) ^ (rb & 7)) * 16);
    }

    f32x4 accf[4][4], accg[4][4];
#pragma unroll
    for (int i = 0; i < 4; i++)
#pragma unroll
        for (int j = 0; j < 4; j++) {
            accf[i][j] = (f32x4){0.f, 0.f, 0.f, 0.f};
            accg[i][j] = (f32x4){0.f, 0.f, 0.f, 0.f};
        }

    for (int k0 = 0; k0 < K; k0 += 128) {
#pragma unroll
        for (int r = 0; r < 4; r++) {
            GLL(agp + (long)r * rowskip, asl + r * 4096);
            GLL(bfgp + (long)r * rowskip, bfl + r * 4096);
            GLL(bggp + (long)r * rowskip, bgl + r * 4096);
        }
        agp += 128; bfgp += 128; bggp += 128;
        __syncthreads();

        i32x8 af[4];
#pragma unroll
        for (int f = 0; f < 4; f++) {
            const i32x4 lo = *(const i32x4*)(As + offA0[f]);
            const i32x4 hi = *(const i32x4*)(As + offA1[f]);
            af[f][0] = lo[0]; af[f][1] = lo[1]; af[f][2] = lo[2]; af[f][3] = lo[3];
            af[f][4] = hi[0]; af[f][5] = hi[1]; af[f][6] = hi[2]; af[f][7] = hi[3];
        }
#pragma unroll
        for (int j = 0; j < 4; j++) {
            i32x8 bfj, bgj;
            {
                const i32x4 lo = *(const i32x4*)(Bfs + offB0[j]);
                const i32x4 hi = *(const i32x4*)(Bfs + offB1[j]);
                bfj[0] = lo[0]; bfj[1] = lo[1]; bfj[2] = lo[2]; bfj[3] = lo[3];
                bfj[4] = hi[0]; bfj[5] = hi[1]; bfj[6] = hi[2]; bfj[7] = hi[3];
            }
            {
                const i32x4 lo = *(const i32x4*)(Bgs + offB0[j]);
                const i32x4 hi = *(const i32x4*)(Bgs + offB1[j]);
                bgj[0] = lo[0]; bgj[1] = lo[1]; bgj[2] = lo[2]; bgj[3] = lo[3];
                bgj[4] = hi[0]; bgj[5] = hi[1]; bgj[6] = hi[2]; bgj[7] = hi[3];
            }
#pragma unroll
            for (int i = 0; i < 4; i++)
                accf[i][j] = __builtin_amdgcn_mfma_scale_f32_16x16x128_f8f6f4(
                    af[i], bfj, accf[i][j], 0, 0, 0, 127, 0, 122);
#pragma unroll
            for (int i = 0; i < 4; i++)
                accg[i][j] = __builtin_amdgcn_mfma_scale_f32_16x16x128_f8f6f4(
                    af[i], bgj, accg[i][j], 0, 0, 0, 127, 0, 122);
        }
        __syncthreads();
    }

    // epilogue: C/D layout col=lane&15, row=(lane>>4)*4+reg (shape-determined)
#pragma unroll
    for (int j = 0; j < 4; j++) {
        const int n = bn0 + wn + j * 16 + lrow;
        const float bfb = biasf[n];
        const float bgb = biasg[n];
#pragma unroll
        for (int i = 0; i < 4; i++) {
#pragma unroll
            for (int r = 0; r < 4; r++) {
                const int m = bm0 + wm + i * 16 + lq * 4 + r;
                const long off = (long)m * N + n;
                const float vf = accf[i][j][r] + bfb;
                const float vg = accg[i][j][r] + bgb;
                const float e = __expf(2.0f * fabsf(vf));
                const float th = copysignf(1.0f - 2.0f / (e + 1.0f), vf);
                const float g = 1.0f / (1.0f + __expf(-vg));
                const float c = fp8_to_f(cat8[off]);
                Out[off] = cmask[m] ? (g * th + (1.0f - g) * c) : NEG_INF_F;
            }
        }
    }
}

// ---------- masked row softmax over LQ=512, in place on bf16 S ----------
__global__ __launch_bounds__(256) void softmax_rows(bf16* __restrict__ S,
                                                    const int* __restrict__ Cmask,
                                                    const int* __restrict__ Qmask) {
    const int row = blockIdx.x;         // 0 .. B*LC-1
    const int b = row >> 11;            // LC = 2048
    const int tid = threadIdx.x;
    bf16* srow = S + (long)row * LQ;
    const int* qm = Qmask + b * LQ;
    __shared__ float red[8];

    if (Cmask[row] == 0) {
        const bf16 u = __float2bfloat16(1.0f / 512.0f);
        srow[tid] = u;
        srow[tid + 256] = u;
        return;
    }
    const int q0 = qm[tid], q1 = qm[tid + 256];
    float v0 = q0 ? __bfloat162float(srow[tid]) : -3e38f;
    float v1 = q1 ? __bfloat162float(srow[tid + 256]) : -3e38f;
    float mx = fmaxf(v0, v1);
#pragma unroll
    for (int o = 32; o > 0; o >>= 1) mx = fmaxf(mx, __shfl_down(mx, o, 64));
    const int wave = tid >> 6, lane = tid & 63;
    if (lane == 0) red[wave] = mx;
    __syncthreads();
    const float m4 = fmaxf(fmaxf(red[0], red[1]), fmaxf(red[2], red[3]));
    float e0 = q0 ? __expf(v0 - m4) : 0.f;
    float e1 = q1 ? __expf(v1 - m4) : 0.f;
    float s = e0 + e1;
#pragma unroll
    for (int o = 32; o > 0; o >>= 1) s += __shfl_down(s, o, 64);
    if (lane == 0) red[4 + wave] = s;
    __syncthreads();
    const float tot = red[4] + red[5] + red[6] + red[7];
    if (!(tot > 0.f)) {
        const bf16 u = __float2bfloat16(1.0f / 512.0f);
        srow[tid] = u;
        srow[tid + 256] = u;
        return;
    }
    const float inv = 1.0f / tot;
    srow[tid] = __float2bfloat16(e0 * inv);
    srow[tid + 256] = __float2bfloat16(e1 * inv);
}

// ---------- build cat = [C | attn | attn-C | attn*C] as fp8 e4m3 ----------
__global__ __launch_bounds__(256) void build_cat(const bf16* __restrict__ Cb,
                                                 const bf16* __restrict__ attn,
                                                 unsigned char* __restrict__ cat8) {
    const long t = (long)blockIdx.x * 256 + threadIdx.x;
    const int m = (int)(t >> 6);
    const int c = (int)(t & 63) << 3;
    const s16x8 cv = *(const s16x8*)((const short*)Cb + (long)m * DIM + c);
    const s16x8 av = *(const s16x8*)((const short*)attn + (long)m * DIM + c);
    float cf[8], af_[8];
#pragma unroll
    for (int i = 0; i < 8; i++) { cf[i] = bfs2f(cv[i]); af_[i] = bfs2f(av[i]); }
    unsigned char* rowp = cat8 + (long)m * FEAT + c;
    *(uint2*)(rowp) = pk8fp8(cf[0], cf[1], cf[2], cf[3], cf[4], cf[5], cf[6], cf[7]);
    *(uint2*)(rowp + 512) = pk8fp8(af_[0], af_[1], af_[2], af_[3], af_[4], af_[5], af_[6], af_[7]);
    *(uint2*)(rowp + 1024) = pk8fp8(af_[0] - cf[0], af_[1] - cf[1], af_[2] - cf[2], af_[3] - cf[3],
                                    af_[4] - cf[4], af_[5] - cf[5], af_[6] - cf[6], af_[7] - cf[7]);
    *(uint2*)(rowp + 1536) = pk8fp8(af_[0] * cf[0], af_[1] * cf[1], af_[2] * cf[2], af_[3] * cf[3],
                                    af_[4] * cf[4], af_[5] * cf[5], af_[6] * cf[6], af_[7] * cf[7]);
}

extern "C" void kernel_launch(void* const* d_in, const int* in_sizes, int n_in,
                              void* d_out, int out_size, void* d_ws, size_t ws_size,
                              hipStream_t stream) {
    (void)in_sizes; (void)n_in; (void)out_size; (void)ws_size;
    const float* C = (const float*)d_in[0];
    const float* Q = (const float*)d_in[1];
    const int* Cmask = (const int*)d_in[2];
    const int* Qmask = (const int*)d_in[3];
    const float* W1 = (const float*)d_in[4];
    const float* b1 = (const float*)d_in[5];
    const float* Wf = (const float*)d_in[6];
    const float* bfp = (const float*)d_in[7];
    const float* Wg = (const float*)d_in[8];
    const float* bgp = (const float*)d_in[9];
    float* out = (float*)d_out;

    // ---- workspace layout (bytes). cat8 overlaps the dead early temps
    // (W1b/Qb/Qt/C_/Q_/S are all last read before build_cat writes cat8). ----
    char* ws = (char*)d_ws;
    unsigned char* cat8 = (unsigned char*)(ws + 0);     //  67,108,864
    bf16* W1b  = (bf16*)(ws + 0);                       //     524,288
    bf16* Qb   = (bf16*)(ws + 524288);                  //   8,388,608
    bf16* Qt   = (bf16*)(ws + 8912896);                 //   8,388,608
    bf16* C_   = (bf16*)(ws + 17301504);                //  33,554,432
    bf16* Q_   = (bf16*)(ws + 50855936);                //   8,388,608
    bf16* S    = (bf16*)(ws + 59244544);                //  33,554,432 (dead before cat8 write)
    bf16* Cb   = (bf16*)(ws + 134217728);               //  33,554,432
    bf16* attn = (bf16*)(ws + 167772160);               //  33,554,432
    unsigned char* Wf8 = (unsigned char*)(ws + 201326592); // 4,194,304
    unsigned char* Wg8 = (unsigned char*)(ws + 205520896); // 4,194,304 (end ~209.7MB)

    // 1. dtype conversions
    cvt_f32_bf16<<<256, 256, 0, stream>>>(W1, W1b, DIM * DIM);
    cvt_f32_fp8_w<<<4096, 256, 0, stream>>>(Wf, Wf8, FEAT * FEAT);
    cvt_f32_fp8_w<<<4096, 256, 0, stream>>>(Wg, Wg8, FEAT * FEAT);
    cvt_f32_bf16<<<16384, 256, 0, stream>>>(C, Cb, MC * DIM);
    cvt_f32_bf16<<<4096, 256, 0, stream>>>(Q, Qb, MQ * DIM);
    transpose_q<<<dim3(16, 16, 16), dim3(32, 8), 0, stream>>>(Q, Qt);

    // 2. C_ = lrelu(C @ W1^T + b1), Q_ = lrelu(Q @ W1^T + b1)  (bf16 out)
    gemm_bt<MODE_BIAS_LRELU><<<dim3(4, 256, 1), 256, 0, stream>>>(
        Cb, W1b, C_, b1, DIM, DIM, 0, 0, 0);
    gemm_bt<MODE_BIAS_LRELU><<<dim3(4, 64, 1), 256, 0, stream>>>(
        Qb, W1b, Q_, b1, DIM, DIM, 0, 0, 0);

    // 3. S[b] = C_[b] @ Q_[b]^T  (batched, bf16 logits)
    gemm_bt<MODE_PLAIN><<<dim3(4, 16, 16), 256, 0, stream>>>(
        C_, Q_, S, nullptr, LQ, DIM,
        (long)LC * DIM, (long)LQ * DIM, (long)LC * LQ);

    // 4. masked softmax over q (in place)
    softmax_rows<<<MC, 256, 0, stream>>>(S, Cmask, Qmask);

    // 5. attn[b] = S[b] @ Q[b]   (B-operand = Qt, batched)
    gemm_bt<MODE_PLAIN><<<dim3(4, 16, 16), 256, 0, stream>>>(
        S, Qt, attn, nullptr, DIM, LQ,
        (long)LC * LQ, (long)DIM * LQ, (long)LC * DIM);

    // 6. cat8 = [C | attn | attn-C | attn*C] (fp8)
    build_cat<<<8192, 256, 0, stream>>>(Cb, attn, cat8);

    // 7+8 fused MX-fp8 dual GEMM + activations + gate blend + Cmask (fp32 out)
    gemm_dual_fp8<<<dim3(16, 256, 1), 256, 0, stream>>>(
        cat8, Wf8, Wg8, out, bfp, bgp, cat8, Cmask);
}